// Round 6
// baseline (569.676 us; speedup 1.0000x reference)
//
#include <hip/hip_runtime.h>
#include <math.h>

#define F_IN 128
#define H_DIM 64
#define C_OUT 40
#define XCDS 8
#define SLICES 96

typedef _Float16 h8 __attribute__((ext_vector_type(8)));  // 16B = 8 fp16 features
typedef float nf4 __attribute__((ext_vector_type(4)));    // native float4 (nt-load-able)

// ---------------- CSR build (XCD-partitioned, nt streaming reads) ----------------

__global__ void __launch_bounds__(256) histx_kernel(const int* __restrict__ dst,
                                                    int* __restrict__ deg, int E, int N) {
    int xcd = blockIdx.x & (XCDS - 1);       // heuristic XCD swizzle (perf only)
    int slice = blockIdx.x >> 3;
    int lo = (int)((long long)N * xcd / XCDS);
    int hi = (int)((long long)N * (xcd + 1) / XCDS);
    int chunk = (E + SLICES - 1) / SLICES;
    int e0 = slice * chunk;
    int e1 = min(E, e0 + chunk);
    for (int e = e0 + (int)threadIdx.x; e < e1; e += 256) {
        int d = __builtin_nontemporal_load(&dst[e]);  // nt: don't evict dirty deg lines
        if (d >= lo && d < hi) atomicAdd(&deg[d], 1);
    }
}

__global__ void scan1_kernel(const int* __restrict__ deg, int* __restrict__ incl,
                             int* __restrict__ bsum, int n) {
    __shared__ int s[256];
    int i = blockIdx.x * 256 + threadIdx.x;
    int v = (i < n) ? deg[i] : 0;
    s[threadIdx.x] = v;
    __syncthreads();
#pragma unroll
    for (int off = 1; off < 256; off <<= 1) {
        int t = (threadIdx.x >= off) ? s[threadIdx.x - off] : 0;
        __syncthreads();
        s[threadIdx.x] += t;
        __syncthreads();
    }
    if (i < n) incl[i] = s[threadIdx.x];
    if (threadIdx.x == 255) bsum[blockIdx.x] = s[255];
}

__global__ void scan2_kernel(const int* __restrict__ bsum, int* __restrict__ boff, int nb) {
    __shared__ int s[512];
    int v = ((int)threadIdx.x < nb) ? bsum[threadIdx.x] : 0;
    s[threadIdx.x] = v;
    __syncthreads();
#pragma unroll
    for (int off = 1; off < 512; off <<= 1) {
        int t = (threadIdx.x >= off) ? s[threadIdx.x - off] : 0;
        __syncthreads();
        s[threadIdx.x] += t;
        __syncthreads();
    }
    if ((int)threadIdx.x < nb) boff[threadIdx.x] = s[threadIdx.x] - v;
}

__global__ void scan3_kernel(const int* __restrict__ incl, const int* __restrict__ deg,
                             const int* __restrict__ boff, int* __restrict__ rowptr,
                             int* __restrict__ cursor, int n) {
    int i = blockIdx.x * 256 + threadIdx.x;
    if (i < n) {
        int b = i >> 8;
        int excl = boff[b] + incl[i] - deg[i];
        rowptr[i] = excl;
        cursor[i] = excl;
        if (i == n - 1) rowptr[n] = boff[b] + incl[i];
    }
}

__global__ void __launch_bounds__(256) scatterx_kernel(const int* __restrict__ src,
                                                       const int* __restrict__ dst,
                                                       int* __restrict__ cursor,
                                                       int* __restrict__ ssrc, int E, int N) {
    int xcd = blockIdx.x & (XCDS - 1);
    int slice = blockIdx.x >> 3;
    int lo = (int)((long long)N * xcd / XCDS);
    int hi = (int)((long long)N * (xcd + 1) / XCDS);
    int chunk = (E + SLICES - 1) / SLICES;
    int e0 = slice * chunk;
    int e1 = min(E, e0 + chunk);
    for (int e = e0 + (int)threadIdx.x; e < e1; e += 256) {
        int d = __builtin_nontemporal_load(&dst[e]);  // nt: preserve dirty ssrc/cursor lines in L2
        if (d >= lo && d < hi) {
            int s = __builtin_nontemporal_load(&src[e]);
            int p = atomicAdd(&cursor[d], 1);
            ssrc[p] = s;  // p in this XCD's contiguous region -> L2-resident line fills
        }
    }
}

// ---------------- lin1: LDS-staged x tile, 32 rows/block, fp16 h out ----------------
__global__ void __launch_bounds__(256) lin1_kernel(
        const float* __restrict__ x, const float* __restrict__ W1,
        const float* __restrict__ b1, _Float16* __restrict__ hout,
        float* __restrict__ rn, int n) {
    __shared__ float sx[32 * F_IN];  // 16 KB
    int tid = threadIdx.x;
    int r0 = blockIdx.x * 32;
    int rows = min(32, n - r0);

    {
        const nf4* xg = (const nf4*)(x + (size_t)r0 * F_IN);
        nf4* sx4 = (nf4*)sx;
        int tot = rows * (F_IN / 4);
        for (int i = tid; i < tot; i += 256) sx4[i] = __builtin_nontemporal_load(&xg[i]);
    }
    __syncthreads();

    int wave = tid >> 6, lane = tid & 63;
    int rbase = wave * 8;
    float bl = b1[lane];
    float acc[8];
#pragma unroll
    for (int j = 0; j < 8; j++) acc[j] = bl;

    const float4* sx4 = (const float4*)sx;
#pragma unroll 2
    for (int k = 0; k < F_IN; k += 4) {
        float w0 = W1[(k + 0) * H_DIM + lane];
        float w1 = W1[(k + 1) * H_DIM + lane];
        float w2 = W1[(k + 2) * H_DIM + lane];
        float w3 = W1[(k + 3) * H_DIM + lane];
#pragma unroll
        for (int j = 0; j < 8; j++) {
            float4 xv = sx4[(rbase + j) * (F_IN / 4) + (k >> 2)];
            acc[j] = fmaf(xv.x, w0, acc[j]);
            acc[j] = fmaf(xv.y, w1, acc[j]);
            acc[j] = fmaf(xv.z, w2, acc[j]);
            acc[j] = fmaf(xv.w, w3, acc[j]);
        }
    }

#pragma unroll
    for (int j = 0; j < 8; j++) {
        int r = rbase + j;
        if (r >= rows) break;
        float a = fmaxf(acc[j], 0.0f);
        hout[(size_t)(r0 + r) * H_DIM + lane] = (_Float16)a;
        float ss = a * a;
#pragma unroll
        for (int k = 1; k < 64; k <<= 1) ss += __shfl_xor(ss, k, 64);
        if (lane == 0) rn[r0 + r] = 1.0f / fmaxf(sqrtf(ss), 1e-12f);
    }
}

// ---------------- AGNN layer: wave/dst, 8 lanes/edge (16B fp16 loads) ----------------
__global__ void __launch_bounds__(256) agnn_kernel(
        const h8* __restrict__ h, const float* __restrict__ rnorm,
        const int* __restrict__ rowptr, const int* __restrict__ ssrc,
        h8* __restrict__ hout, float* __restrict__ rnout, int n) {
    int wid = (blockIdx.x * blockDim.x + threadIdx.x) >> 6;
    int t = threadIdx.x & 63;
    if (wid >= n) return;
    int g = t >> 3;    // edge group 0..7
    int sub = t & 7;   // feature chunk (8 halves = 16B)

    h8 hd16 = h[(size_t)wid * 8 + sub];
    float hd[8];
#pragma unroll
    for (int i = 0; i < 8; i++) hd[i] = (float)hd16[i];
    float rni = rnorm[wid];

    float dself = 0.0f;
#pragma unroll
    for (int i = 0; i < 8; i++) dself = fmaf(hd[i], hd[i], dself);
#pragma unroll
    for (int k = 1; k < 8; k <<= 1) dself += __shfl_xor(dself, k, 64);
    float wself = __expf(dself * rni * rni);

    float acc[8];
    float sw = (g == 0) ? wself : 0.0f;
#pragma unroll
    for (int i = 0; i < 8; i++) acc[i] = (g == 0) ? wself * hd[i] : 0.0f;

    int e = rowptr[wid] + g;
    int end = rowptr[wid + 1];

    for (; e + 8 < end; e += 16) {
        int s0 = ssrc[e];
        int s1 = ssrc[e + 8];
        h8 a16 = h[(size_t)s0 * 8 + sub];
        h8 b16 = h[(size_t)s1 * 8 + sub];
        float rn0 = rnorm[s0];
        float rn1 = rnorm[s1];
        float av[8], bv[8];
#pragma unroll
        for (int i = 0; i < 8; i++) { av[i] = (float)a16[i]; bv[i] = (float)b16[i]; }
        float d0 = 0.0f, d1 = 0.0f;
#pragma unroll
        for (int i = 0; i < 8; i++) { d0 = fmaf(av[i], hd[i], d0); d1 = fmaf(bv[i], hd[i], d1); }
#pragma unroll
        for (int k = 1; k < 8; k <<= 1) {
            d0 += __shfl_xor(d0, k, 64);
            d1 += __shfl_xor(d1, k, 64);
        }
        float w0 = __expf(d0 * rni * rn0);
        float w1 = __expf(d1 * rni * rn1);
#pragma unroll
        for (int i = 0; i < 8; i++) acc[i] = fmaf(w0, av[i], fmaf(w1, bv[i], acc[i]));
        sw += w0 + w1;
    }
    for (; e < end; e += 8) {
        int s0 = ssrc[e];
        h8 a16 = h[(size_t)s0 * 8 + sub];
        float rn0 = rnorm[s0];
        float av[8];
#pragma unroll
        for (int i = 0; i < 8; i++) av[i] = (float)a16[i];
        float d0 = 0.0f;
#pragma unroll
        for (int i = 0; i < 8; i++) d0 = fmaf(av[i], hd[i], d0);
#pragma unroll
        for (int k = 1; k < 8; k <<= 1) d0 += __shfl_xor(d0, k, 64);
        float w0 = __expf(d0 * rni * rn0);
#pragma unroll
        for (int i = 0; i < 8; i++) acc[i] = fmaf(w0, av[i], acc[i]);
        sw += w0;
    }

#pragma unroll
    for (int k = 8; k < 64; k <<= 1) {
#pragma unroll
        for (int i = 0; i < 8; i++) acc[i] += __shfl_xor(acc[i], k, 64);
        sw += __shfl_xor(sw, k, 64);
    }
    float inv = 1.0f / sw;
    float o[8];
#pragma unroll
    for (int i = 0; i < 8; i++) o[i] = acc[i] * inv;
    if (g == 0) {
        h8 oh;
#pragma unroll
        for (int i = 0; i < 8; i++) oh[i] = (_Float16)o[i];
        hout[(size_t)wid * 8 + sub] = oh;
    }
    float ss = 0.0f;
#pragma unroll
    for (int i = 0; i < 8; i++) ss = fmaf(o[i], o[i], ss);
#pragma unroll
    for (int k = 1; k < 8; k <<= 1) ss += __shfl_xor(ss, k, 64);
    if (t == 0) rnout[wid] = 1.0f / fmaxf(sqrtf(ss), 1e-12f);
}

// ---------------- lin2 + log_softmax: fp16 input, LDS-staged, 32 rows/block ----------------
__global__ void __launch_bounds__(256) lin2_kernel(
        const h8* __restrict__ h, const float* __restrict__ W2,
        const float* __restrict__ b2, float* __restrict__ out, int n) {
    __shared__ h8 sh[32 * 8];  // 4 KB
    int tid = threadIdx.x;
    int r0 = blockIdx.x * 32;
    int rows = min(32, n - r0);

    {
        const uint4* hg = (const uint4*)(h + (size_t)r0 * 8);
        uint4* sh4 = (uint4*)sh;
        int tot = rows * 8;
        for (int i = tid; i < tot; i += 256) sh4[i] = hg[i];
    }
    __syncthreads();

    int wave = tid >> 6, lane = tid & 63;
    int rbase = wave * 8;

    float acc[8];
    if (lane < C_OUT) {
        float bl = b2[lane];
#pragma unroll
        for (int j = 0; j < 8; j++) acc[j] = bl;
#pragma unroll 2
        for (int k = 0; k < H_DIM; k += 8) {
            float w[8];
#pragma unroll
            for (int i = 0; i < 8; i++) w[i] = W2[(k + i) * C_OUT + lane];
#pragma unroll
            for (int j = 0; j < 8; j++) {
                h8 hv = sh[(rbase + j) * 8 + (k >> 3)];
#pragma unroll
                for (int i = 0; i < 8; i++) acc[j] = fmaf((float)hv[i], w[i], acc[j]);
            }
        }
    } else {
#pragma unroll
        for (int j = 0; j < 8; j++) acc[j] = -INFINITY;
    }

#pragma unroll
    for (int j = 0; j < 8; j++) {
        int r = rbase + j;
        if (r >= rows) break;
        float m = acc[j];
#pragma unroll
        for (int k = 1; k < 64; k <<= 1) m = fmaxf(m, __shfl_xor(m, k, 64));
        float e = (lane < C_OUT) ? __expf(acc[j] - m) : 0.0f;
        float s = e;
#pragma unroll
        for (int k = 1; k < 64; k <<= 1) s += __shfl_xor(s, k, 64);
        if (lane < C_OUT) out[(size_t)(r0 + r) * C_OUT + lane] = acc[j] - m - logf(s);
    }
}

// ---------------- launch ----------------

extern "C" void kernel_launch(void* const* d_in, const int* in_sizes, int n_in,
                              void* d_out, int out_size, void* d_ws, size_t ws_size,
                              hipStream_t stream) {
    const float* x = (const float*)d_in[0];
    const float* W1 = (const float*)d_in[1];
    const float* b1 = (const float*)d_in[2];
    const float* W2 = (const float*)d_in[3];
    const float* b2 = (const float*)d_in[4];
    const int* ei = (const int*)d_in[5];

    const int N = in_sizes[0] / F_IN;      // 100000
    const int E = in_sizes[5] / 2;         // 1600000
    const int* src = ei;
    const int* dst = ei + E;

    char* w = (char*)d_ws;
    auto carve = [&](size_t bytes) {
        char* p = w;
        w += (bytes + 255) & ~(size_t)255;
        return p;
    };
    _Float16* g1 = (_Float16*)carve((size_t)N * H_DIM * 2);
    _Float16* g2 = (_Float16*)carve((size_t)N * H_DIM * 2);
    float* rn1 = (float*)carve((size_t)N * 4);
    float* rn2 = (float*)carve((size_t)N * 4);
    int* deg = (int*)carve((size_t)N * 4);
    int* incl = (int*)carve((size_t)N * 4);
    int* rowptr = (int*)carve((size_t)(N + 1) * 4);
    int* cursor = (int*)carve((size_t)N * 4);
    int* bsum = (int*)carve(1024 * 4);
    int* boff = (int*)carve(1024 * 4);
    int* ssrc = (int*)carve((size_t)E * 4);

    const int nb = (N + 255) / 256;

    // CSR build (XCD-partitioned hist + scatter, nt streaming reads)
    (void)hipMemsetAsync(deg, 0, (size_t)N * 4, stream);
    histx_kernel<<<XCDS * SLICES, 256, 0, stream>>>(dst, deg, E, N);
    scan1_kernel<<<nb, 256, 0, stream>>>(deg, incl, bsum, N);
    scan2_kernel<<<1, 512, 0, stream>>>(bsum, boff, nb);
    scan3_kernel<<<nb, 256, 0, stream>>>(incl, deg, boff, rowptr, cursor, N);
    scatterx_kernel<<<XCDS * SLICES, 256, 0, stream>>>(src, dst, cursor, ssrc, E, N);

    // lin1 (+rnorm), fp16 h out
    lin1_kernel<<<(N + 31) / 32, 256, 0, stream>>>(x, W1, b1, g1, rn1, N);

    // 4 AGNN layers, ping-pong on fp16 h
    {
        int blocks = (N * 64 + 255) / 256;
        agnn_kernel<<<blocks, 256, 0, stream>>>((const h8*)g1, rn1, rowptr, ssrc, (h8*)g2, rn2, N);
        agnn_kernel<<<blocks, 256, 0, stream>>>((const h8*)g2, rn2, rowptr, ssrc, (h8*)g1, rn1, N);
        agnn_kernel<<<blocks, 256, 0, stream>>>((const h8*)g1, rn1, rowptr, ssrc, (h8*)g2, rn2, N);
        agnn_kernel<<<blocks, 256, 0, stream>>>((const h8*)g2, rn2, rowptr, ssrc, (h8*)g1, rn1, N);
    }

    // lin2 + log_softmax
    lin2_kernel<<<(N + 31) / 32, 256, 0, stream>>>((const h8*)g1, W2, b2, (float*)d_out, N);
}

// Round 7
// 440.071 us; speedup vs baseline: 1.2945x; 1.2945x over previous
//
#include <hip/hip_runtime.h>
#include <math.h>

#define F_IN 128
#define H_DIM 64
#define C_OUT 40
#define NBK 391          // ceil(100000/256) coarse buckets, 256 nodes each
#define CHUNK 4096       // edges per binscatter block

typedef _Float16 h8 __attribute__((ext_vector_type(8)));  // 16B = 8 fp16 features
typedef float nf4 __attribute__((ext_vector_type(4)));    // native float4 (nt-load-able)

// ---------------- CSR build: two-level LDS counting sort ----------------

// Phase 1: coarse bucket histogram (bucket = dst >> 8)
__global__ void __launch_bounds__(256) bhist_kernel(const int* __restrict__ dst,
                                                    int* __restrict__ bhist, int E) {
    __shared__ int lh[512];
    int tid = threadIdx.x;
    lh[tid] = 0; lh[tid + 256] = 0;
    __syncthreads();
    int stride = gridDim.x * 256;
    for (int e = blockIdx.x * 256 + tid; e < E; e += stride) {
        int d = __builtin_nontemporal_load(&dst[e]);
        atomicAdd(&lh[d >> 8], 1);
    }
    __syncthreads();
    if (lh[tid]) atomicAdd(&bhist[tid], lh[tid]);
    if (lh[tid + 256]) atomicAdd(&bhist[tid + 256], lh[tid + 256]);
}

// Phase 2: scan bucket sizes -> bbase (exclusive), init bcursor
__global__ void __launch_bounds__(512) bscan_kernel(const int* __restrict__ bhist,
                                                    int* __restrict__ bbase,
                                                    int* __restrict__ bcursor, int E) {
    __shared__ int sa[512], sb[512];
    int t = threadIdx.x;
    int v = (t < NBK) ? bhist[t] : 0;
    sa[t] = v;
    __syncthreads();
    int* pa = sa; int* pb = sb;
#pragma unroll
    for (int off = 1; off < 512; off <<= 1) {
        pb[t] = pa[t] + ((t >= off) ? pa[t - off] : 0);
        __syncthreads();
        int* tmp = pa; pa = pb; pb = tmp;
    }
    if (t < NBK) {
        int excl = pa[t] - v;
        bbase[t] = excl;
        bcursor[t] = excl;
    }
    if (t == 0) bbase[NBK] = E;
}

// Phase 3: bin edges into buckets; LDS counting sort per chunk, contiguous run writes
__global__ void __launch_bounds__(256) binscatter_kernel(const int* __restrict__ src,
                                                         const int* __restrict__ dst,
                                                         int* __restrict__ bcursor,
                                                         int2* __restrict__ pairs, int E) {
    __shared__ int2 sp[CHUNK];
    __shared__ unsigned short sbof[CHUNK];
    __shared__ int hist[512];
    __shared__ int scanA[512], scanB[512];
    __shared__ int cur[512];
    __shared__ int gbase[512];
    int tid = threadIdx.x;
    int e0 = blockIdx.x * CHUNK;
    int cnt = min(CHUNK, E - e0);

    int dv[CHUNK / 256], sv[CHUNK / 256];
#pragma unroll
    for (int i = 0; i < CHUNK / 256; i++) {
        int idx = tid + i * 256;
        if (idx < cnt) {
            dv[i] = __builtin_nontemporal_load(&dst[e0 + idx]);
            sv[i] = __builtin_nontemporal_load(&src[e0 + idx]);
        }
    }
    hist[tid] = 0; hist[tid + 256] = 0;
    __syncthreads();
#pragma unroll
    for (int i = 0; i < CHUNK / 256; i++) {
        int idx = tid + i * 256;
        if (idx < cnt) atomicAdd(&hist[dv[i] >> 8], 1);
    }
    __syncthreads();
    scanA[tid] = hist[tid]; scanA[tid + 256] = hist[tid + 256];
    __syncthreads();
    int* pa = scanA; int* pb = scanB;
#pragma unroll
    for (int off = 1; off < 512; off <<= 1) {
        pb[tid] = pa[tid] + ((tid >= off) ? pa[tid - off] : 0);
        int t1 = tid + 256;
        pb[t1] = pa[t1] + ((t1 >= off) ? pa[t1 - off] : 0);
        __syncthreads();
        int* tmp = pa; pa = pb; pb = tmp;
    }
    // excl[b] = pa[b] - hist[b]
    cur[tid] = pa[tid] - hist[tid];
    cur[tid + 256] = pa[tid + 256] - hist[tid + 256];
    __syncthreads();
    // local scatter into LDS (sorted by bucket)
#pragma unroll
    for (int i = 0; i < CHUNK / 256; i++) {
        int idx = tid + i * 256;
        if (idx < cnt) {
            int b = dv[i] >> 8;
            int lp = atomicAdd(&cur[b], 1);
            sp[lp] = make_int2(dv[i], sv[i]);
            sbof[lp] = (unsigned short)b;
        }
    }
    // reserve global runs: one atomic per touched bucket
    {
        int c0 = hist[tid];
        gbase[tid] = c0 ? atomicAdd(&bcursor[tid], c0) : 0;
        int c1 = hist[tid + 256];
        gbase[tid + 256] = c1 ? atomicAdd(&bcursor[tid + 256], c1) : 0;
    }
    __syncthreads();
    // copy out: consecutive i within a bucket run -> consecutive global addresses
    for (int i = tid; i < cnt; i += 256) {
        int b = sbof[i];
        int off_in_b = i - (pa[b] - hist[b]);
        pairs[gbase[b] + off_in_b] = sp[i];
    }
}

// Phase 4: per-bucket exact sort: rowptr + ssrc (bucket output window = 16 KB, L2-local)
__global__ void __launch_bounds__(256) bucketsort_kernel(const int2* __restrict__ pairs,
                                                         const int* __restrict__ bbase,
                                                         int* __restrict__ rowptr,
                                                         int* __restrict__ ssrc, int N, int E) {
    __shared__ int hist[256], scanA[256], scanB[256], cur[256];
    int b = blockIdx.x;
    int tid = threadIdx.x;
    int e0 = bbase[b], e1 = bbase[b + 1];
    hist[tid] = 0;
    __syncthreads();
    for (int e = e0 + tid; e < e1; e += 256) {
        int2 p = pairs[e];
        atomicAdd(&hist[p.x & 255], 1);
    }
    __syncthreads();
    scanA[tid] = hist[tid];
    __syncthreads();
    int* pa = scanA; int* pb = scanB;
#pragma unroll
    for (int off = 1; off < 256; off <<= 1) {
        pb[tid] = pa[tid] + ((tid >= off) ? pa[tid - off] : 0);
        __syncthreads();
        int* tmp = pa; pa = pb; pb = tmp;
    }
    int excl = pa[tid] - hist[tid];
    int node = (b << 8) + tid;
    if (node < N) rowptr[node] = e0 + excl;
    if (b == NBK - 1 && tid == 0) rowptr[N] = E;
    cur[tid] = e0 + excl;
    __syncthreads();
    for (int e = e0 + tid; e < e1; e += 256) {
        int2 p = pairs[e];
        int pos = atomicAdd(&cur[p.x & 255], 1);
        ssrc[pos] = p.y;
    }
}

// ---------------- lin1: LDS-staged x tile, 32 rows/block, fp16 h out ----------------
__global__ void __launch_bounds__(256) lin1_kernel(
        const float* __restrict__ x, const float* __restrict__ W1,
        const float* __restrict__ b1, _Float16* __restrict__ hout,
        float* __restrict__ rn, int n) {
    __shared__ float sx[32 * F_IN];  // 16 KB
    int tid = threadIdx.x;
    int r0 = blockIdx.x * 32;
    int rows = min(32, n - r0);

    {
        const nf4* xg = (const nf4*)(x + (size_t)r0 * F_IN);
        nf4* sx4 = (nf4*)sx;
        int tot = rows * (F_IN / 4);
        for (int i = tid; i < tot; i += 256) sx4[i] = __builtin_nontemporal_load(&xg[i]);
    }
    __syncthreads();

    int wave = tid >> 6, lane = tid & 63;
    int rbase = wave * 8;
    float bl = b1[lane];
    float acc[8];
#pragma unroll
    for (int j = 0; j < 8; j++) acc[j] = bl;

    const float4* sx4 = (const float4*)sx;
#pragma unroll 2
    for (int k = 0; k < F_IN; k += 4) {
        float w0 = W1[(k + 0) * H_DIM + lane];
        float w1 = W1[(k + 1) * H_DIM + lane];
        float w2 = W1[(k + 2) * H_DIM + lane];
        float w3 = W1[(k + 3) * H_DIM + lane];
#pragma unroll
        for (int j = 0; j < 8; j++) {
            float4 xv = sx4[(rbase + j) * (F_IN / 4) + (k >> 2)];
            acc[j] = fmaf(xv.x, w0, acc[j]);
            acc[j] = fmaf(xv.y, w1, acc[j]);
            acc[j] = fmaf(xv.z, w2, acc[j]);
            acc[j] = fmaf(xv.w, w3, acc[j]);
        }
    }

#pragma unroll
    for (int j = 0; j < 8; j++) {
        int r = rbase + j;
        if (r >= rows) break;
        float a = fmaxf(acc[j], 0.0f);
        hout[(size_t)(r0 + r) * H_DIM + lane] = (_Float16)a;
        float ss = a * a;
#pragma unroll
        for (int k = 1; k < 64; k <<= 1) ss += __shfl_xor(ss, k, 64);
        if (lane == 0) rn[r0 + r] = 1.0f / fmaxf(sqrtf(ss), 1e-12f);
    }
}

// ---------------- AGNN layer: wave/dst, 8 lanes/edge (16B fp16 loads) ----------------
__global__ void __launch_bounds__(256) agnn_kernel(
        const h8* __restrict__ h, const float* __restrict__ rnorm,
        const int* __restrict__ rowptr, const int* __restrict__ ssrc,
        h8* __restrict__ hout, float* __restrict__ rnout, int n) {
    int wid = (blockIdx.x * blockDim.x + threadIdx.x) >> 6;
    int t = threadIdx.x & 63;
    if (wid >= n) return;
    int g = t >> 3;    // edge group 0..7
    int sub = t & 7;   // feature chunk (8 halves = 16B)

    h8 hd16 = h[(size_t)wid * 8 + sub];
    float hd[8];
#pragma unroll
    for (int i = 0; i < 8; i++) hd[i] = (float)hd16[i];
    float rni = rnorm[wid];

    float dself = 0.0f;
#pragma unroll
    for (int i = 0; i < 8; i++) dself = fmaf(hd[i], hd[i], dself);
#pragma unroll
    for (int k = 1; k < 8; k <<= 1) dself += __shfl_xor(dself, k, 64);
    float wself = __expf(dself * rni * rni);

    float acc[8];
    float sw = (g == 0) ? wself : 0.0f;
#pragma unroll
    for (int i = 0; i < 8; i++) acc[i] = (g == 0) ? wself * hd[i] : 0.0f;

    int e = rowptr[wid] + g;
    int end = rowptr[wid + 1];

    for (; e + 8 < end; e += 16) {
        int s0 = ssrc[e];
        int s1 = ssrc[e + 8];
        h8 a16 = h[(size_t)s0 * 8 + sub];
        h8 b16 = h[(size_t)s1 * 8 + sub];
        float rn0 = rnorm[s0];
        float rn1 = rnorm[s1];
        float av[8], bv[8];
#pragma unroll
        for (int i = 0; i < 8; i++) { av[i] = (float)a16[i]; bv[i] = (float)b16[i]; }
        float d0 = 0.0f, d1 = 0.0f;
#pragma unroll
        for (int i = 0; i < 8; i++) { d0 = fmaf(av[i], hd[i], d0); d1 = fmaf(bv[i], hd[i], d1); }
#pragma unroll
        for (int k = 1; k < 8; k <<= 1) {
            d0 += __shfl_xor(d0, k, 64);
            d1 += __shfl_xor(d1, k, 64);
        }
        float w0 = __expf(d0 * rni * rn0);
        float w1 = __expf(d1 * rni * rn1);
#pragma unroll
        for (int i = 0; i < 8; i++) acc[i] = fmaf(w0, av[i], fmaf(w1, bv[i], acc[i]));
        sw += w0 + w1;
    }
    for (; e < end; e += 8) {
        int s0 = ssrc[e];
        h8 a16 = h[(size_t)s0 * 8 + sub];
        float rn0 = rnorm[s0];
        float av[8];
#pragma unroll
        for (int i = 0; i < 8; i++) av[i] = (float)a16[i];
        float d0 = 0.0f;
#pragma unroll
        for (int i = 0; i < 8; i++) d0 = fmaf(av[i], hd[i], d0);
#pragma unroll
        for (int k = 1; k < 8; k <<= 1) d0 += __shfl_xor(d0, k, 64);
        float w0 = __expf(d0 * rni * rn0);
#pragma unroll
        for (int i = 0; i < 8; i++) acc[i] = fmaf(w0, av[i], acc[i]);
        sw += w0;
    }

#pragma unroll
    for (int k = 8; k < 64; k <<= 1) {
#pragma unroll
        for (int i = 0; i < 8; i++) acc[i] += __shfl_xor(acc[i], k, 64);
        sw += __shfl_xor(sw, k, 64);
    }
    float inv = 1.0f / sw;
    float o[8];
#pragma unroll
    for (int i = 0; i < 8; i++) o[i] = acc[i] * inv;
    if (g == 0) {
        h8 oh;
#pragma unroll
        for (int i = 0; i < 8; i++) oh[i] = (_Float16)o[i];
        hout[(size_t)wid * 8 + sub] = oh;
    }
    float ss = 0.0f;
#pragma unroll
    for (int i = 0; i < 8; i++) ss = fmaf(o[i], o[i], ss);
#pragma unroll
    for (int k = 1; k < 8; k <<= 1) ss += __shfl_xor(ss, k, 64);
    if (t == 0) rnout[wid] = 1.0f / fmaxf(sqrtf(ss), 1e-12f);
}

// ---------------- lin2 + log_softmax: fp16 input, LDS-staged, 32 rows/block ----------------
__global__ void __launch_bounds__(256) lin2_kernel(
        const h8* __restrict__ h, const float* __restrict__ W2,
        const float* __restrict__ b2, float* __restrict__ out, int n) {
    __shared__ h8 sh[32 * 8];  // 4 KB
    int tid = threadIdx.x;
    int r0 = blockIdx.x * 32;
    int rows = min(32, n - r0);

    {
        const uint4* hg = (const uint4*)(h + (size_t)r0 * 8);
        uint4* sh4 = (uint4*)sh;
        int tot = rows * 8;
        for (int i = tid; i < tot; i += 256) sh4[i] = hg[i];
    }
    __syncthreads();

    int wave = tid >> 6, lane = tid & 63;
    int rbase = wave * 8;

    float acc[8];
    if (lane < C_OUT) {
        float bl = b2[lane];
#pragma unroll
        for (int j = 0; j < 8; j++) acc[j] = bl;
#pragma unroll 2
        for (int k = 0; k < H_DIM; k += 8) {
            float w[8];
#pragma unroll
            for (int i = 0; i < 8; i++) w[i] = W2[(k + i) * C_OUT + lane];
#pragma unroll
            for (int j = 0; j < 8; j++) {
                h8 hv = sh[(rbase + j) * 8 + (k >> 3)];
#pragma unroll
                for (int i = 0; i < 8; i++) acc[j] = fmaf((float)hv[i], w[i], acc[j]);
            }
        }
    } else {
#pragma unroll
        for (int j = 0; j < 8; j++) acc[j] = -INFINITY;
    }

#pragma unroll
    for (int j = 0; j < 8; j++) {
        int r = rbase + j;
        if (r >= rows) break;
        float m = acc[j];
#pragma unroll
        for (int k = 1; k < 64; k <<= 1) m = fmaxf(m, __shfl_xor(m, k, 64));
        float e = (lane < C_OUT) ? __expf(acc[j] - m) : 0.0f;
        float s = e;
#pragma unroll
        for (int k = 1; k < 64; k <<= 1) s += __shfl_xor(s, k, 64);
        if (lane < C_OUT) out[(size_t)(r0 + r) * C_OUT + lane] = acc[j] - m - logf(s);
    }
}

// ---------------- launch ----------------

extern "C" void kernel_launch(void* const* d_in, const int* in_sizes, int n_in,
                              void* d_out, int out_size, void* d_ws, size_t ws_size,
                              hipStream_t stream) {
    const float* x = (const float*)d_in[0];
    const float* W1 = (const float*)d_in[1];
    const float* b1 = (const float*)d_in[2];
    const float* W2 = (const float*)d_in[3];
    const float* b2 = (const float*)d_in[4];
    const int* ei = (const int*)d_in[5];

    const int N = in_sizes[0] / F_IN;      // 100000
    const int E = in_sizes[5] / 2;         // 1600000
    const int* src = ei;
    const int* dst = ei + E;

    char* w = (char*)d_ws;
    auto carve = [&](size_t bytes) {
        char* p = w;
        w += (bytes + 255) & ~(size_t)255;
        return p;
    };
    _Float16* g1 = (_Float16*)carve((size_t)N * H_DIM * 2);
    _Float16* g2 = (_Float16*)carve((size_t)N * H_DIM * 2);   // also aliased as pairs (dead before agnn L1)
    float* rn1 = (float*)carve((size_t)N * 4);
    float* rn2 = (float*)carve((size_t)N * 4);
    int* rowptr = (int*)carve((size_t)(N + 1) * 4);
    int* bhist = (int*)carve(512 * 4);
    int* bbase = (int*)carve(512 * 4);
    int* bcursor = (int*)carve(512 * 4);
    int* ssrc = (int*)carve((size_t)E * 4);
    int2* pairs = (int2*)g2;   // 12.8 MB alias: pairs used only during CSR build

    // CSR build: two-level LDS counting sort (all writes structurally coalesced)
    (void)hipMemsetAsync(bhist, 0, 512 * 4, stream);
    bhist_kernel<<<512, 256, 0, stream>>>(dst, bhist, E);
    bscan_kernel<<<1, 512, 0, stream>>>(bhist, bbase, bcursor, E);
    binscatter_kernel<<<(E + CHUNK - 1) / CHUNK, 256, 0, stream>>>(src, dst, bcursor, pairs, E);
    bucketsort_kernel<<<NBK, 256, 0, stream>>>(pairs, bbase, rowptr, ssrc, N, E);

    // lin1 (+rnorm), fp16 h out
    lin1_kernel<<<(N + 31) / 32, 256, 0, stream>>>(x, W1, b1, g1, rn1, N);

    // 4 AGNN layers, ping-pong on fp16 h
    {
        int blocks = (N * 64 + 255) / 256;
        agnn_kernel<<<blocks, 256, 0, stream>>>((const h8*)g1, rn1, rowptr, ssrc, (h8*)g2, rn2, N);
        agnn_kernel<<<blocks, 256, 0, stream>>>((const h8*)g2, rn2, rowptr, ssrc, (h8*)g1, rn1, N);
        agnn_kernel<<<blocks, 256, 0, stream>>>((const h8*)g1, rn1, rowptr, ssrc, (h8*)g2, rn2, N);
        agnn_kernel<<<blocks, 256, 0, stream>>>((const h8*)g2, rn2, rowptr, ssrc, (h8*)g1, rn1, N);
    }

    // lin2 + log_softmax
    lin2_kernel<<<(N + 31) / 32, 256, 0, stream>>>((const h8*)g1, W2, b2, (float*)d_out, N);
}